// Round 1
// baseline (16357.274 us; speedup 1.0000x reference)
//
#include <hip/hip_runtime.h>

// OR_LSTM: 2-layer LSTM autoregressive rollout, wavefront-pipelined.
// B=32, T=128, D=16, H=256, WS=8, OUT=8. 120 windows, pipelined over 127
// global iterations: at iter g, windows g-7..g each advance one LSTM step
// (8 slots x 32 batch = 256 rows). 2 grid barriers per iteration.

#define NWG 256
#define TPB 256

// ---- workspace layout ----
// u32 indices:
#define REL_U     4160            // release word (flags occupy u32 [0,4096))
// float indices:
#define H0A_F     8192
#define H0B_F     (H0A_F + 65536)
#define C0_F      (H0B_F + 65536)
#define H1A_F     (C0_F + 65536)
#define H1B_F     (H1A_F + 65536)
#define C1_F      (H1B_F + 65536)
#define WTHH0_F   (C1_F + 65536)          // [256][1024] transposed
#define WTIH1_F   (WTHH0_F + 262144)      // [256][1024]
#define WTHH1_F   (WTIH1_F + 262144)      // [256][1024]
#define WTIH0_F   (WTHH1_F + 262144)      // [16][1024]
// total ~4.82 MB of d_ws

__device__ __forceinline__ float sigf(float x) { return 1.0f / (1.0f + __expf(-x)); }
__device__ __forceinline__ float tanhfast(float x) {
  float e = __expf(2.0f * x);
  return 1.0f - 2.0f / (e + 1.0f);
}

// Grid barrier: each wg posts its own flag line; wg0 polls all and releases.
// Monotonic phases, flags/rel zeroed by hipMemsetAsync each launch.
__device__ __forceinline__ void gridbar(unsigned* flags, unsigned* rel, unsigned ph) {
  __syncthreads();
  __threadfence();
  const int tid = threadIdx.x;
  if (blockIdx.x == 0) {
    for (;;) {
      int ok = 1;
      if (tid != 0)
        ok = (__hip_atomic_load(&flags[tid * 16], __ATOMIC_ACQUIRE,
                                __HIP_MEMORY_SCOPE_AGENT) >= ph);
      if (__syncthreads_and(ok)) break;
    }
    __threadfence();
    if (tid == 0)
      __hip_atomic_store(rel, ph, __ATOMIC_RELEASE, __HIP_MEMORY_SCOPE_AGENT);
    __syncthreads();
  } else {
    if (tid == 0) {
      __hip_atomic_store(&flags[blockIdx.x * 16], ph, __ATOMIC_RELEASE,
                         __HIP_MEMORY_SCOPE_AGENT);
      while (__hip_atomic_load(rel, __ATOMIC_ACQUIRE,
                               __HIP_MEMORY_SCOPE_AGENT) < ph)
        __builtin_amdgcn_s_sleep(1);
    }
    __syncthreads();
  }
}

// Transpose weights into ws: WT[k][j] = W[j][k] (coalesced k-loop loads later).
__global__ __launch_bounds__(256) void lstm_prep(
    const float* __restrict__ Wih0, const float* __restrict__ Whh0,
    const float* __restrict__ Wih1, const float* __restrict__ Whh1,
    float* __restrict__ wsf) {
  const int i = blockIdx.x * 256 + threadIdx.x;
  if (i < 262144) {
    const int k = i >> 10, j = i & 1023;
    wsf[WTHH0_F + i] = Whh0[j * 256 + k];
    wsf[WTIH1_F + i] = Wih1[j * 256 + k];
    wsf[WTHH1_F + i] = Whh1[j * 256 + k];
    if (k < 16) wsf[WTIH0_F + i] = Wih0[j * 16 + k];
  }
}

__global__ __launch_bounds__(TPB) void lstm_main(
    const float* __restrict__ traj,
    const float* __restrict__ bih0, const float* __restrict__ bhh0,
    const float* __restrict__ bih1, const float* __restrict__ bhh1,
    const float* __restrict__ Wlin, const float* __restrict__ blin,
    float* __restrict__ out, float* __restrict__ wsf) {
  // LDS: sh_a (4096) | sh_bp (8200: B-tile first 4096 / partials) |
  //      sh_x (256) | sh_g (1024) | sh_hn (256)  => 13832 floats = 55.3 KB
  __shared__ float smem[13832];
  float* sh_a  = smem;
  float* sh_bp = smem + 4096;
  float* sh_x  = smem + 12296;
  float* sh_g  = smem + 12552;
  float* sh_hn = smem + 13576;

  const int tid = threadIdx.x;
  const int wg  = blockIdx.x;
  const int rt  = wg >> 4;        // row tile (16 rows each), 0..15
  const int uc  = wg & 15;        // unit chunk (16 hidden units), 0..15
  const int slotId  = rt >> 1;    // pipeline slot 0..7
  const int rowBase = rt << 4;

  const int ks  = tid >> 5;       // K-split 0..7
  const int cg  = tid & 31;
  const int g01 = cg >> 4;        // gate 0/1 (pairs with gate+2)
  const int ul  = cg & 15;        // unit within chunk
  const int j1  = g01 * 256 + uc * 16 + ul;
  const int j2  = j1 + 512;
  const int lc1 = g01 * 16 + ul;  // local col 0..31 (and +32)

  unsigned* flags = (unsigned*)wsf;
  unsigned* rel   = ((unsigned*)wsf) + REL_U;

  const float* WT_hh0 = wsf + WTHH0_F;
  const float* WT_ih1 = wsf + WTIH1_F;
  const float* WT_hh1 = wsf + WTHH1_F;
  const float* WT_ih0 = wsf + WTIH0_F;

  unsigned ph = 0;
  float acc1[16], acc2[16];

  for (int g = 0; g < 127; ++g) {
    const int s = (g - slotId) & 7;       // step of this slot's window
    const int t = g - s;                  // window index
    const bool valid = (t >= 0) && (t <= 119);
    const bool fresh = (s == 0) || (!valid);  // state must read as zero
    const int p = g & 1;                  // read parity for h buffers

    // ================= PHASE A : layer 0 =================
    {  // stage x[16 rows][16]
      const int r = tid >> 4, d = tid & 15;
      const int b = (rowBase + r) & 31;
      float xv = 0.0f;
      if (valid) {
        if (t <= 7 && s < 8 - t) {
          xv = traj[b * 2048 + (t + s) * 16 + d];          // raw window
        } else if (d < 8) {
          const int ti = (t <= 7) ? (2 * t + s - 1) : (t + s);
          xv = traj[b * 2048 + ti * 16 + d];               // ctrl half
        } else {
          xv = out[b * 960 + (t + s - 8) * 8 + (d - 8)];   // fed-back preds
        }
      }
      sh_x[tid] = xv;
    }
    {  // stage h0 (prev step) -> sh_a, zeros on window start
      const float* h0r = wsf + (p ? H0B_F : H0A_F) + rowBase * 256;
      float4* A4 = (float4*)sh_a;
#pragma unroll
      for (int i = 0; i < 4; ++i) {
        const int idx = tid + i * 256;
        const int r = idx >> 6, q = idx & 63;
        float4 v = make_float4(0.f, 0.f, 0.f, 0.f);
        if (!fresh) v = ((const float4*)h0r)[r * 64 + q];
        A4[r * 64 + q] = v;
      }
    }
    // out-column init: out[:,tf] = (tf==0 ? traj[:,7,8:] : out[:,tf-1]) + b_lin
    if (wg == 0) {
      const int tf = g - 7;
      if (tf >= 0) {
        const int b = tid >> 3, o = tid & 7;
        const float base = (tf == 0) ? traj[b * 2048 + 7 * 16 + 8 + o]
                                     : out[b * 960 + (tf - 1) * 8 + o];
        out[b * 960 + tf * 8 + o] = base + blin[o];
      }
    }
    __syncthreads();

#pragma unroll
    for (int r = 0; r < 16; ++r) { acc1[r] = 0.f; acc2[r] = 0.f; }
    {  // x part, K=16 (2 k's per ks)
#pragma unroll
      for (int kk = 0; kk < 2; ++kk) {
        const int k = ks * 2 + kk;
        const float w1 = WT_ih0[k * 1024 + j1];
        const float w2 = WT_ih0[k * 1024 + j2];
#pragma unroll
        for (int r = 0; r < 16; ++r) {
          const float xv = sh_x[r * 16 + k];
          acc1[r] = fmaf(xv, w1, acc1[r]);
          acc2[r] = fmaf(xv, w2, acc2[r]);
        }
      }
    }
    {  // h part, K=256 (32 k's per ks, unrolled by 4 via float4 LDS reads)
      const float* W = WT_hh0 + ks * 32 * 1024;
      const float4* A4 = (const float4*)sh_a;
#pragma unroll 2
      for (int kc = 0; kc < 8; ++kc) {
        const int kb = kc * 4;
        const float w10 = W[(kb + 0) * 1024 + j1];
        const float w11 = W[(kb + 1) * 1024 + j1];
        const float w12 = W[(kb + 2) * 1024 + j1];
        const float w13 = W[(kb + 3) * 1024 + j1];
        const float w20 = W[(kb + 0) * 1024 + j2];
        const float w21 = W[(kb + 1) * 1024 + j2];
        const float w22 = W[(kb + 2) * 1024 + j2];
        const float w23 = W[(kb + 3) * 1024 + j2];
#pragma unroll
        for (int r = 0; r < 16; ++r) {
          const float4 h4 = A4[r * 64 + ks * 8 + kc];
          acc1[r] = fmaf(h4.x, w10, acc1[r]);
          acc1[r] = fmaf(h4.y, w11, acc1[r]);
          acc1[r] = fmaf(h4.z, w12, acc1[r]);
          acc1[r] = fmaf(h4.w, w13, acc1[r]);
          acc2[r] = fmaf(h4.x, w20, acc2[r]);
          acc2[r] = fmaf(h4.y, w21, acc2[r]);
          acc2[r] = fmaf(h4.z, w22, acc2[r]);
          acc2[r] = fmaf(h4.w, w23, acc2[r]);
        }
      }
    }
    {  // partials -> LDS (plane stride 1025 breaks 8-way bank aliasing)
#pragma unroll
      for (int r = 0; r < 16; ++r) {
        sh_bp[ks * 1025 + r * 64 + lc1]      = acc1[r];
        sh_bp[ks * 1025 + r * 64 + lc1 + 32] = acc2[r];
      }
    }
    __syncthreads();
    {  // reduce K-splits + bias -> sh_g[16][64]
#pragma unroll
      for (int e = 0; e < 4; ++e) {
        const int oi = tid + e * 256;
        const int r = oi >> 6, lc = oi & 63;
        const int j = (lc >> 4) * 256 + uc * 16 + (lc & 15);
        float sum = bih0[j] + bhh0[j];
#pragma unroll
        for (int kq = 0; kq < 8; ++kq) sum += sh_bp[kq * 1025 + r * 64 + lc];
        sh_g[r * 64 + lc] = sum;
      }
    }
    __syncthreads();
    {  // LSTM update, layer 0 (write parity = p^1)
      const int r = tid >> 4, u = tid & 15;
      const int grow = rowBase + r;
      const int gu = uc * 16 + u;
      const float iv = sh_g[r * 64 + u];
      const float fv = sh_g[r * 64 + 16 + u];
      const float gv = sh_g[r * 64 + 32 + u];
      const float ov = sh_g[r * 64 + 48 + u];
      const float cold = fresh ? 0.f : wsf[C0_F + grow * 256 + gu];
      const float cn = sigf(fv) * cold + sigf(iv) * tanhfast(gv);
      const float hn = sigf(ov) * tanhfast(cn);
      wsf[C0_F + grow * 256 + gu] = cn;
      wsf[(p ? H0A_F : H0B_F) + grow * 256 + gu] = hn;
    }
    gridbar(flags, rel, ++ph);

    // ================= PHASE B : layer 1 =================
    {  // stage h0' (this iter's layer-0 output) -> sh_a ; h1 prev -> sh_bp
      const float* h0w = wsf + (p ? H0A_F : H0B_F) + rowBase * 256;
      const float* h1r = wsf + (p ? H1B_F : H1A_F) + rowBase * 256;
      float4* A4 = (float4*)sh_a;
      float4* B4 = (float4*)sh_bp;
#pragma unroll
      for (int i = 0; i < 4; ++i) {
        const int idx = tid + i * 256;
        const int r = idx >> 6, q = idx & 63;
        A4[r * 64 + q] = ((const float4*)h0w)[r * 64 + q];
        float4 v = make_float4(0.f, 0.f, 0.f, 0.f);
        if (!fresh) v = ((const float4*)h1r)[r * 64 + q];
        B4[r * 64 + q] = v;
      }
    }
    __syncthreads();

#pragma unroll
    for (int r = 0; r < 16; ++r) { acc1[r] = 0.f; acc2[r] = 0.f; }
    {  // fused x-GEMM (h0' @ Wih1^T) + h-GEMM (h1 @ Whh1^T)
      const float* Wi = WT_ih1 + ks * 32 * 1024;
      const float* Wh = WT_hh1 + ks * 32 * 1024;
      const float4* A4 = (const float4*)sh_a;
      const float4* B4 = (const float4*)sh_bp;
#pragma unroll 2
      for (int kc = 0; kc < 8; ++kc) {
        const int kb = kc * 4;
        const float wa0 = Wi[(kb + 0) * 1024 + j1];
        const float wa1 = Wi[(kb + 1) * 1024 + j1];
        const float wa2 = Wi[(kb + 2) * 1024 + j1];
        const float wa3 = Wi[(kb + 3) * 1024 + j1];
        const float wa4 = Wi[(kb + 0) * 1024 + j2];
        const float wa5 = Wi[(kb + 1) * 1024 + j2];
        const float wa6 = Wi[(kb + 2) * 1024 + j2];
        const float wa7 = Wi[(kb + 3) * 1024 + j2];
        const float wb0 = Wh[(kb + 0) * 1024 + j1];
        const float wb1 = Wh[(kb + 1) * 1024 + j1];
        const float wb2 = Wh[(kb + 2) * 1024 + j1];
        const float wb3 = Wh[(kb + 3) * 1024 + j1];
        const float wb4 = Wh[(kb + 0) * 1024 + j2];
        const float wb5 = Wh[(kb + 1) * 1024 + j2];
        const float wb6 = Wh[(kb + 2) * 1024 + j2];
        const float wb7 = Wh[(kb + 3) * 1024 + j2];
#pragma unroll
        for (int r = 0; r < 16; ++r) {
          const float4 a4 = A4[r * 64 + ks * 8 + kc];
          const float4 b4 = B4[r * 64 + ks * 8 + kc];
          acc1[r] = fmaf(a4.x, wa0, acc1[r]);
          acc1[r] = fmaf(a4.y, wa1, acc1[r]);
          acc1[r] = fmaf(a4.z, wa2, acc1[r]);
          acc1[r] = fmaf(a4.w, wa3, acc1[r]);
          acc1[r] = fmaf(b4.x, wb0, acc1[r]);
          acc1[r] = fmaf(b4.y, wb1, acc1[r]);
          acc1[r] = fmaf(b4.z, wb2, acc1[r]);
          acc1[r] = fmaf(b4.w, wb3, acc1[r]);
          acc2[r] = fmaf(a4.x, wa4, acc2[r]);
          acc2[r] = fmaf(a4.y, wa5, acc2[r]);
          acc2[r] = fmaf(a4.z, wa6, acc2[r]);
          acc2[r] = fmaf(a4.w, wa7, acc2[r]);
          acc2[r] = fmaf(b4.x, wb4, acc2[r]);
          acc2[r] = fmaf(b4.y, wb5, acc2[r]);
          acc2[r] = fmaf(b4.z, wb6, acc2[r]);
          acc2[r] = fmaf(b4.w, wb7, acc2[r]);
        }
      }
    }
    __syncthreads();  // sh_bp: B-tile dead, reuse as partials
    {
#pragma unroll
      for (int r = 0; r < 16; ++r) {
        sh_bp[ks * 1025 + r * 64 + lc1]      = acc1[r];
        sh_bp[ks * 1025 + r * 64 + lc1 + 32] = acc2[r];
      }
    }
    __syncthreads();
    {
#pragma unroll
      for (int e = 0; e < 4; ++e) {
        const int oi = tid + e * 256;
        const int r = oi >> 6, lc = oi & 63;
        const int j = (lc >> 4) * 256 + uc * 16 + (lc & 15);
        float sum = bih1[j] + bhh1[j];
#pragma unroll
        for (int kq = 0; kq < 8; ++kq) sum += sh_bp[kq * 1025 + r * 64 + lc];
        sh_g[r * 64 + lc] = sum;
      }
    }
    __syncthreads();
    {  // LSTM update, layer 1 (+ keep h' in LDS for head)
      const int r = tid >> 4, u = tid & 15;
      const int grow = rowBase + r;
      const int gu = uc * 16 + u;
      const float iv = sh_g[r * 64 + u];
      const float fv = sh_g[r * 64 + 16 + u];
      const float gv = sh_g[r * 64 + 32 + u];
      const float ov = sh_g[r * 64 + 48 + u];
      const float cold = fresh ? 0.f : wsf[C1_F + grow * 256 + gu];
      const float cn = sigf(fv) * cold + sigf(iv) * tanhfast(gv);
      const float hn = sigf(ov) * tanhfast(cn);
      wsf[C1_F + grow * 256 + gu] = cn;
      wsf[(p ? H1A_F : H1B_F) + grow * 256 + gu] = hn;
      sh_hn[r * 16 + u] = hn;
    }
    __syncthreads();
    {  // head for the finishing window: out[:,tf] += h1' @ Wlin^T (partial/uc)
      const int tf = g - 7;
      if (tf >= 0 && slotId == (tf & 7) && tid < 128) {
        const int rl = tid >> 3, o = tid & 7;
        float sum = 0.f;
#pragma unroll
        for (int u = 0; u < 16; ++u)
          sum += sh_hn[rl * 16 + u] * Wlin[o * 256 + uc * 16 + u];
        const int b = ((rt & 1) << 4) + rl;
        atomicAdd(&out[b * 960 + tf * 8 + o], sum);
      }
    }
    gridbar(flags, rel, ++ph);
  }

  // ---- final h_n/c_n: window 119 lives in slot 7 (rows 224..255);
  //      last write parity is buffer B (g=126 even). 32 wgs copy 32768 floats.
  if (wg < 32) {
    const int i = (wg * 256 + tid) * 4;   // 0..32767, step 4
    const int part = i >> 14;             // 0: h_n, 1: c_n
    const int l = (i >> 13) & 1;          // layer
    const int b = (i >> 8) & 31;
    const int u = i & 255;
    const float* src =
        (part == 0) ? (l == 0 ? wsf + H0B_F : wsf + H1B_F)
                    : (l == 0 ? wsf + C0_F  : wsf + C1_F);
    const float4 v = *(const float4*)(src + (224 + b) * 256 + u);
    *(float4*)(out + 30720 + i) = v;
  }
}

extern "C" void kernel_launch(void* const* d_in, const int* in_sizes, int n_in,
                              void* d_out, int out_size, void* d_ws, size_t ws_size,
                              hipStream_t stream) {
  (void)in_sizes; (void)n_in; (void)out_size; (void)ws_size;
  const float* traj = (const float*)d_in[0];
  const float* Wih0 = (const float*)d_in[1];
  const float* Whh0 = (const float*)d_in[2];
  const float* bih0 = (const float*)d_in[3];
  const float* bhh0 = (const float*)d_in[4];
  const float* Wih1 = (const float*)d_in[5];
  const float* Whh1 = (const float*)d_in[6];
  const float* bih1 = (const float*)d_in[7];
  const float* bhh1 = (const float*)d_in[8];
  const float* Wlin = (const float*)d_in[9];
  const float* blin = (const float*)d_in[10];
  float* out = (float*)d_out;
  float* wsf = (float*)d_ws;

  // zero barrier flags + release word (ws is 0xAA-poisoned each launch)
  hipMemsetAsync(d_ws, 0, 32768, stream);
  lstm_prep<<<1024, 256, 0, stream>>>(Wih0, Whh0, Wih1, Whh1, wsf);

  void* args[] = {(void*)&traj, (void*)&bih0, (void*)&bhh0, (void*)&bih1,
                  (void*)&bhh1, (void*)&Wlin, (void*)&blin, (void*)&out,
                  (void*)&wsf};
  hipLaunchCooperativeKernel((void*)lstm_main, dim3(NWG), dim3(TPB), args, 0,
                             stream);
}

// Round 2
// 6533.144 us; speedup vs baseline: 2.5037x; 2.5037x over previous
//
#include <hip/hip_runtime.h>

// OR_LSTM: 2-layer LSTM autoregressive rollout, wavefront-pipelined.
// B=32, T=128, D=16, H=256, WS=8, OUT=8. 120 windows over 127 iterations;
// at iter g, slots 0..7 (windows g-7..g) each advance one step.
// Round 2: NO grid barriers. Per-rt-group (16 wg) counter barriers +
// per-out-column producer/consumer handshake with replicated ready lines.

#define NWG 256
#define TPB 256

// ---- control region (u32 indices, zeroed by hipMemsetAsync) ----
#define GRP_U(grp) ((grp) * 16)          // 16 group barrier counters
#define END_U      512                    // epilogue sync counter
#define PCNT_U(c)  (1024 + (c) * 16)      // per-column contributor count
#define RDY_U(r)   (4096 + (r) * 16)      // 16 replicated ready lines
#define PSUM_F     8192                   // float idx: psum[120][256]
#define CTRL_BYTES 163840                 // floats [0, 40960) zeroed

// ---- float indices ----
#define H0A_F     40960
#define H0B_F     (H0A_F + 65536)
#define C0_F      (H0B_F + 65536)
#define H1A_F     (C0_F + 65536)
#define H1B_F     (H1A_F + 65536)
#define C1_F      (H1B_F + 65536)
#define WTHH0_F   (C1_F + 65536)          // [256][1024] transposed
#define WTIH1_F   (WTHH0_F + 262144)
#define WTHH1_F   (WTIH1_F + 262144)
#define WTIH0_F   (WTHH1_F + 262144)      // [16][1024]
// total 1236992 floats ~= 4.72 MiB

__device__ __forceinline__ float sigf(float x) { return 1.0f / (1.0f + __expf(-x)); }
__device__ __forceinline__ float tanhfast(float x) {
  float e = __expf(2.0f * x);
  return 1.0f - 2.0f / (e + 1.0f);
}

__device__ __forceinline__ unsigned aload(const unsigned* p) {
  return __hip_atomic_load(p, __ATOMIC_ACQUIRE, __HIP_MEMORY_SCOPE_AGENT);
}

// 16-wg barrier on one counter line; target is monotone (phase*16).
__device__ __forceinline__ void groupbar(unsigned* cnt, unsigned target) {
  __syncthreads();
  if (threadIdx.x == 0) {
    __threadfence();
    atomicAdd(cnt, 1u);
    while (aload(cnt) < target) __builtin_amdgcn_s_sleep(1);
  }
  __syncthreads();
}

// Transpose weights into ws: WT[k][j] = W[j][k].
__global__ __launch_bounds__(256) void lstm_prep(
    const float* __restrict__ Wih0, const float* __restrict__ Whh0,
    const float* __restrict__ Wih1, const float* __restrict__ Whh1,
    float* __restrict__ wsf) {
  const int i = blockIdx.x * 256 + threadIdx.x;
  if (i < 262144) {
    const int k = i >> 10, j = i & 1023;
    wsf[WTHH0_F + i] = Whh0[j * 256 + k];
    wsf[WTIH1_F + i] = Wih1[j * 256 + k];
    wsf[WTHH1_F + i] = Whh1[j * 256 + k];
    if (k < 16) wsf[WTIH0_F + i] = Wih0[j * 16 + k];
  }
}

__global__ __launch_bounds__(TPB) void lstm_main(
    const float* __restrict__ traj,
    const float* __restrict__ bih0, const float* __restrict__ bhh0,
    const float* __restrict__ bih1, const float* __restrict__ bhh1,
    const float* __restrict__ Wlin, const float* __restrict__ blin,
    float* __restrict__ out, float* __restrict__ wsf) {
  __shared__ float smem[13832];
  float* sh_a  = smem;
  float* sh_bp = smem + 4096;
  float* sh_x  = smem + 12296;
  float* sh_g  = smem + 12552;
  float* sh_hn = smem + 13576;

  const int tid = threadIdx.x;
  const int wg  = blockIdx.x;
  const int rt  = wg >> 4;        // row tile (16 rows), 0..15 == group id
  const int uc  = wg & 15;        // unit chunk (16 hidden units)
  const int slotId  = rt >> 1;    // pipeline slot 0..7
  const int rowBase = rt << 4;

  const int ks  = tid >> 5;       // K-split 0..7
  const int cg  = tid & 31;
  const int g01 = cg >> 4;
  const int ul  = cg & 15;
  const int j1  = g01 * 256 + uc * 16 + ul;
  const int j2  = j1 + 512;
  const int lc1 = g01 * 16 + ul;

  unsigned* ctrl = (unsigned*)wsf;
  unsigned* gcnt = &ctrl[GRP_U(rt)];

  const float* WT_hh0 = wsf + WTHH0_F;
  const float* WT_ih1 = wsf + WTIH1_F;
  const float* WT_hh1 = wsf + WTHH1_F;
  const float* WT_ih0 = wsf + WTIH0_F;

  unsigned bar = 0;
  float acc1[16], acc2[16];

  for (int g = 0; g < 127; ++g) {
    const int s = (g - slotId) & 7;
    const int t = g - s;
    const bool valid = (t >= 0) && (t <= 119);
    const bool fresh = (s == 0) || (!valid);
    const int p = g & 1;

    // ================= PHASE A : layer 0 =================
    if (g >= 8) {  // need out[:, g-8] finalized
      if (tid == 0) {
        const unsigned need = (unsigned)(g - 7);
        while (aload(&ctrl[RDY_U(rt)]) < need) __builtin_amdgcn_s_sleep(2);
      }
      __syncthreads();
    }
    {  // stage x[16 rows][16]
      const int r = tid >> 4, d = tid & 15;
      const int b = (rowBase + r) & 31;
      float xv = 0.0f;
      if (valid) {
        if (t <= 7 && s < 8 - t) {
          xv = traj[b * 2048 + (t + s) * 16 + d];
        } else if (d < 8) {
          const int ti = (t <= 7) ? (2 * t + s - 1) : (t + s);
          xv = traj[b * 2048 + ti * 16 + d];
        } else {
          xv = out[b * 960 + (t + s - 8) * 8 + (d - 8)];
        }
      }
      sh_x[tid] = xv;
    }
    {  // stage h0prev
      const float* h0r = wsf + (p ? H0B_F : H0A_F) + rowBase * 256;
      float4* A4 = (float4*)sh_a;
#pragma unroll
      for (int i = 0; i < 4; ++i) {
        const int idx = tid + i * 256;
        const int r = idx >> 6, q = idx & 63;
        float4 v = make_float4(0.f, 0.f, 0.f, 0.f);
        if (!fresh) v = ((const float4*)h0r)[r * 64 + q];
        A4[r * 64 + q] = v;
      }
    }
    __syncthreads();

#pragma unroll
    for (int r = 0; r < 16; ++r) { acc1[r] = 0.f; acc2[r] = 0.f; }
    {  // x part, K=16
#pragma unroll
      for (int kk = 0; kk < 2; ++kk) {
        const int k = ks * 2 + kk;
        const float w1 = WT_ih0[k * 1024 + j1];
        const float w2 = WT_ih0[k * 1024 + j2];
#pragma unroll
        for (int r = 0; r < 16; ++r) {
          const float xv = sh_x[r * 16 + k];
          acc1[r] = fmaf(xv, w1, acc1[r]);
          acc2[r] = fmaf(xv, w2, acc2[r]);
        }
      }
    }
    {  // h part, K=256
      const float* W = WT_hh0 + ks * 32 * 1024;
      const float4* A4 = (const float4*)sh_a;
#pragma unroll 2
      for (int kc = 0; kc < 8; ++kc) {
        const int kb = kc * 4;
        const float w10 = W[(kb + 0) * 1024 + j1];
        const float w11 = W[(kb + 1) * 1024 + j1];
        const float w12 = W[(kb + 2) * 1024 + j1];
        const float w13 = W[(kb + 3) * 1024 + j1];
        const float w20 = W[(kb + 0) * 1024 + j2];
        const float w21 = W[(kb + 1) * 1024 + j2];
        const float w22 = W[(kb + 2) * 1024 + j2];
        const float w23 = W[(kb + 3) * 1024 + j2];
#pragma unroll
        for (int r = 0; r < 16; ++r) {
          const float4 h4 = A4[r * 64 + ks * 8 + kc];
          acc1[r] = fmaf(h4.x, w10, acc1[r]);
          acc1[r] = fmaf(h4.y, w11, acc1[r]);
          acc1[r] = fmaf(h4.z, w12, acc1[r]);
          acc1[r] = fmaf(h4.w, w13, acc1[r]);
          acc2[r] = fmaf(h4.x, w20, acc2[r]);
          acc2[r] = fmaf(h4.y, w21, acc2[r]);
          acc2[r] = fmaf(h4.z, w22, acc2[r]);
          acc2[r] = fmaf(h4.w, w23, acc2[r]);
        }
      }
    }
    {
#pragma unroll
      for (int r = 0; r < 16; ++r) {
        sh_bp[ks * 1025 + r * 64 + lc1]      = acc1[r];
        sh_bp[ks * 1025 + r * 64 + lc1 + 32] = acc2[r];
      }
    }
    __syncthreads();
    {
#pragma unroll
      for (int e = 0; e < 4; ++e) {
        const int oi = tid + e * 256;
        const int r = oi >> 6, lc = oi & 63;
        const int j = (lc >> 4) * 256 + uc * 16 + (lc & 15);
        float sum = bih0[j] + bhh0[j];
#pragma unroll
        for (int kq = 0; kq < 8; ++kq) sum += sh_bp[kq * 1025 + r * 64 + lc];
        sh_g[r * 64 + lc] = sum;
      }
    }
    __syncthreads();
    {  // LSTM update, layer 0
      const int r = tid >> 4, u = tid & 15;
      const int grow = rowBase + r;
      const int gu = uc * 16 + u;
      const float iv = sh_g[r * 64 + u];
      const float fv = sh_g[r * 64 + 16 + u];
      const float gv = sh_g[r * 64 + 32 + u];
      const float ov = sh_g[r * 64 + 48 + u];
      const float cold = fresh ? 0.f : wsf[C0_F + grow * 256 + gu];
      const float cn = sigf(fv) * cold + sigf(iv) * tanhfast(gv);
      const float hn = sigf(ov) * tanhfast(cn);
      wsf[C0_F + grow * 256 + gu] = cn;
      wsf[(p ? H0A_F : H0B_F) + grow * 256 + gu] = hn;
    }
    bar += 16;
    groupbar(gcnt, bar);

    // ================= PHASE B : layer 1 =================
    {
      const float* h0w = wsf + (p ? H0A_F : H0B_F) + rowBase * 256;
      const float* h1r = wsf + (p ? H1B_F : H1A_F) + rowBase * 256;
      float4* A4 = (float4*)sh_a;
      float4* B4 = (float4*)sh_bp;
#pragma unroll
      for (int i = 0; i < 4; ++i) {
        const int idx = tid + i * 256;
        const int r = idx >> 6, q = idx & 63;
        A4[r * 64 + q] = ((const float4*)h0w)[r * 64 + q];
        float4 v = make_float4(0.f, 0.f, 0.f, 0.f);
        if (!fresh) v = ((const float4*)h1r)[r * 64 + q];
        B4[r * 64 + q] = v;
      }
    }
    __syncthreads();

#pragma unroll
    for (int r = 0; r < 16; ++r) { acc1[r] = 0.f; acc2[r] = 0.f; }
    {
      const float* Wi = WT_ih1 + ks * 32 * 1024;
      const float* Wh = WT_hh1 + ks * 32 * 1024;
      const float4* A4 = (const float4*)sh_a;
      const float4* B4 = (const float4*)sh_bp;
#pragma unroll 2
      for (int kc = 0; kc < 8; ++kc) {
        const int kb = kc * 4;
        const float wa0 = Wi[(kb + 0) * 1024 + j1];
        const float wa1 = Wi[(kb + 1) * 1024 + j1];
        const float wa2 = Wi[(kb + 2) * 1024 + j1];
        const float wa3 = Wi[(kb + 3) * 1024 + j1];
        const float wa4 = Wi[(kb + 0) * 1024 + j2];
        const float wa5 = Wi[(kb + 1) * 1024 + j2];
        const float wa6 = Wi[(kb + 2) * 1024 + j2];
        const float wa7 = Wi[(kb + 3) * 1024 + j2];
        const float wb0 = Wh[(kb + 0) * 1024 + j1];
        const float wb1 = Wh[(kb + 1) * 1024 + j1];
        const float wb2 = Wh[(kb + 2) * 1024 + j1];
        const float wb3 = Wh[(kb + 3) * 1024 + j1];
        const float wb4 = Wh[(kb + 0) * 1024 + j2];
        const float wb5 = Wh[(kb + 1) * 1024 + j2];
        const float wb6 = Wh[(kb + 2) * 1024 + j2];
        const float wb7 = Wh[(kb + 3) * 1024 + j2];
#pragma unroll
        for (int r = 0; r < 16; ++r) {
          const float4 a4 = A4[r * 64 + ks * 8 + kc];
          const float4 b4 = B4[r * 64 + ks * 8 + kc];
          acc1[r] = fmaf(a4.x, wa0, acc1[r]);
          acc1[r] = fmaf(a4.y, wa1, acc1[r]);
          acc1[r] = fmaf(a4.z, wa2, acc1[r]);
          acc1[r] = fmaf(a4.w, wa3, acc1[r]);
          acc1[r] = fmaf(b4.x, wb0, acc1[r]);
          acc1[r] = fmaf(b4.y, wb1, acc1[r]);
          acc1[r] = fmaf(b4.z, wb2, acc1[r]);
          acc1[r] = fmaf(b4.w, wb3, acc1[r]);
          acc2[r] = fmaf(a4.x, wa4, acc2[r]);
          acc2[r] = fmaf(a4.y, wa5, acc2[r]);
          acc2[r] = fmaf(a4.z, wa6, acc2[r]);
          acc2[r] = fmaf(a4.w, wa7, acc2[r]);
          acc2[r] = fmaf(b4.x, wb4, acc2[r]);
          acc2[r] = fmaf(b4.y, wb5, acc2[r]);
          acc2[r] = fmaf(b4.z, wb6, acc2[r]);
          acc2[r] = fmaf(b4.w, wb7, acc2[r]);
        }
      }
    }
    __syncthreads();
    {
#pragma unroll
      for (int r = 0; r < 16; ++r) {
        sh_bp[ks * 1025 + r * 64 + lc1]      = acc1[r];
        sh_bp[ks * 1025 + r * 64 + lc1 + 32] = acc2[r];
      }
    }
    __syncthreads();
    {
#pragma unroll
      for (int e = 0; e < 4; ++e) {
        const int oi = tid + e * 256;
        const int r = oi >> 6, lc = oi & 63;
        const int j = (lc >> 4) * 256 + uc * 16 + (lc & 15);
        float sum = bih1[j] + bhh1[j];
#pragma unroll
        for (int kq = 0; kq < 8; ++kq) sum += sh_bp[kq * 1025 + r * 64 + lc];
        sh_g[r * 64 + lc] = sum;
      }
    }
    __syncthreads();
    {  // LSTM update, layer 1
      const int r = tid >> 4, u = tid & 15;
      const int grow = rowBase + r;
      const int gu = uc * 16 + u;
      const float iv = sh_g[r * 64 + u];
      const float fv = sh_g[r * 64 + 16 + u];
      const float gv = sh_g[r * 64 + 32 + u];
      const float ov = sh_g[r * 64 + 48 + u];
      const float cold = fresh ? 0.f : wsf[C1_F + grow * 256 + gu];
      const float cn = sigf(fv) * cold + sigf(iv) * tanhfast(gv);
      const float hn = sigf(ov) * tanhfast(cn);
      wsf[C1_F + grow * 256 + gu] = cn;
      wsf[(p ? H1A_F : H1B_F) + grow * 256 + gu] = hn;
      sh_hn[r * 16 + u] = hn;
    }
    __syncthreads();
    {  // head + column finalize handshake
      const int tf = g - 7;
      const bool isHead = (tf >= 0) && (slotId == (tf & 7));
      if (isHead) {
        if (tid < 128) {
          const int rl = tid >> 3, o = tid & 7;
          float sum = 0.f;
#pragma unroll
          for (int u = 0; u < 16; ++u)
            sum += sh_hn[rl * 16 + u] * Wlin[o * 256 + uc * 16 + u];
          const int b = ((rt & 1) << 4) + rl;
          atomicAdd(&wsf[PSUM_F + tf * 256 + b * 8 + o], sum);
        }
        __syncthreads();
        if (tid == 0) {
          __threadfence();
          atomicAdd(&ctrl[PCNT_U(tf)], 1u);
        }
        if (((rt & 1) == 1) && (uc == 15)) {  // finisher wg
          if (tid == 0)
            while (aload(&ctrl[PCNT_U(tf)]) < 32u) __builtin_amdgcn_s_sleep(1);
          __syncthreads();
          const int b = tid >> 3, o = tid & 7;
          const float base = (tf == 0) ? traj[b * 2048 + 7 * 16 + 8 + o]
                                       : out[b * 960 + (tf - 1) * 8 + o];
          out[b * 960 + tf * 8 + o] = base + blin[o] + wsf[PSUM_F + tf * 256 + tid];
          __syncthreads();
          if (tid < 16) {
            __threadfence();
            __hip_atomic_store(&ctrl[RDY_U(tid)], (unsigned)(tf + 1),
                               __ATOMIC_RELEASE, __HIP_MEMORY_SCOPE_AGENT);
          }
        }
      }
    }
    bar += 16;
    groupbar(gcnt, bar);
  }

  // ---- epilogue: h_n/c_n for window 119 (rows 224..255, buffers B).
  //      Done by groups 14/15 only, after a 32-wg end sync.
  if (rt >= 14) {
    if (tid == 0) {
      __threadfence();
      atomicAdd(&ctrl[END_U], 1u);
      while (aload(&ctrl[END_U]) < 32u) __builtin_amdgcn_s_sleep(2);
    }
    __syncthreads();
    const int idx = (rt - 14) * 16 + uc;   // 0..31
    const int i = idx * 1024 + tid * 4;    // 0..32767, step 4
    const int part = i >> 14;
    const int l = (i >> 13) & 1;
    const int b = (i >> 8) & 31;
    const int u = i & 255;
    const float* src =
        (part == 0) ? (l == 0 ? wsf + H0B_F : wsf + H1B_F)
                    : (l == 0 ? wsf + C0_F  : wsf + C1_F);
    const float4 v = *(const float4*)(src + (224 + b) * 256 + u);
    *(float4*)(out + 30720 + i) = v;
  }
}

extern "C" void kernel_launch(void* const* d_in, const int* in_sizes, int n_in,
                              void* d_out, int out_size, void* d_ws, size_t ws_size,
                              hipStream_t stream) {
  (void)in_sizes; (void)n_in; (void)out_size; (void)ws_size;
  const float* traj = (const float*)d_in[0];
  const float* Wih0 = (const float*)d_in[1];
  const float* Whh0 = (const float*)d_in[2];
  const float* bih0 = (const float*)d_in[3];
  const float* bhh0 = (const float*)d_in[4];
  const float* Wih1 = (const float*)d_in[5];
  const float* Whh1 = (const float*)d_in[6];
  const float* bih1 = (const float*)d_in[7];
  const float* bhh1 = (const float*)d_in[8];
  const float* Wlin = (const float*)d_in[9];
  const float* blin = (const float*)d_in[10];
  float* out = (float*)d_out;
  float* wsf = (float*)d_ws;

  // zero control region (group counters, pcnt, rdy, psum)
  hipMemsetAsync(d_ws, 0, CTRL_BYTES, stream);
  lstm_prep<<<1024, 256, 0, stream>>>(Wih0, Whh0, Wih1, Whh1, wsf);

  void* args[] = {(void*)&traj, (void*)&bih0, (void*)&bhh0, (void*)&bih1,
                  (void*)&bhh1, (void*)&Wlin, (void*)&blin, (void*)&out,
                  (void*)&wsf};
  hipLaunchCooperativeKernel((void*)lstm_main, dim3(NWG), dim3(TPB), args, 0,
                             stream);
}

// Round 3
// 6386.694 us; speedup vs baseline: 2.5611x; 1.0229x over previous
//
#include <hip/hip_runtime.h>

// OR_LSTM: 2-layer LSTM autoregressive rollout, wavefront-pipelined.
// B=32, T=128, D=16, H=256, WS=8, OUT=8. 120 windows over 127 iterations;
// at iter g, slots 0..7 (windows g-7..g) each advance one step.
// Round 3: per-wg PACKED weights (L2-resident dense 64KB slices, float4/lane)
// + 512 threads/wg (2 waves/SIMD latency hiding). Per-group barriers only.

#define NWG 256
#define TPB 512

// ---- control region (u32 indices, zeroed by hipMemsetAsync) ----
#define GRP_U(grp) ((grp) * 16)          // 16 group barrier counters
#define END_U      512                    // epilogue sync counter
#define PCNT_U(c)  (1024 + (c) * 16)      // per-column contributor count
#define RDY_U(r)   (4096 + (r) * 16)      // 16 replicated ready lines
#define PSUM_F     8192                   // float idx: psum[120][256]
#define CTRL_BYTES 163840                 // floats [0, 40960) zeroed

// ---- float indices ----
#define H0A_F     40960
#define H0B_F     (H0A_F + 65536)
#define C0_F      (H0B_F + 65536)
#define H1A_F     (C0_F + 65536)
#define H1B_F     (H1A_F + 65536)
#define C1_F      (H1B_F + 65536)
// packed weights: PW[uc][kb4][c][kk]  (uc stride 16384, float4 per (kb4,c))
#define PWHH0_F   (C1_F + 65536)
#define PWIH1_F   (PWHH0_F + 262144)
#define PWHH1_F   (PWIH1_F + 262144)
#define PWIH0_F   (PWHH1_F + 262144)      // [uc][k][c], k<16 (uc stride 1024)
// total 1236992 floats ~= 4.72 MiB

__device__ __forceinline__ float sigf(float x) { return 1.0f / (1.0f + __expf(-x)); }
__device__ __forceinline__ float tanhfast(float x) {
  float e = __expf(2.0f * x);
  return 1.0f - 2.0f / (e + 1.0f);
}

__device__ __forceinline__ unsigned aload(const unsigned* p) {
  return __hip_atomic_load(p, __ATOMIC_ACQUIRE, __HIP_MEMORY_SCOPE_AGENT);
}

// 16-wg barrier on one counter line; target is monotone (phase*16).
__device__ __forceinline__ void groupbar(unsigned* cnt, unsigned target) {
  __syncthreads();
  if (threadIdx.x == 0) {
    __threadfence();
    atomicAdd(cnt, 1u);
    while (aload(cnt) < target) __builtin_amdgcn_s_sleep(1);
  }
  __syncthreads();
}

// Pack weights: PW[uc][kb4][c][kk] = W[j(c,uc)][kb4*4+kk], j = gate(c)*256+uc*16+unit(c).
__global__ __launch_bounds__(256) void lstm_prep(
    const float* __restrict__ Wih0, const float* __restrict__ Whh0,
    const float* __restrict__ Wih1, const float* __restrict__ Whh1,
    float* __restrict__ wsf) {
  const int i = blockIdx.x * 256 + threadIdx.x;
  if (i < 262144) {
    const int uc  = i >> 14;
    const int kb4 = (i >> 8) & 63;
    const int c   = (i >> 2) & 63;
    const int kk  = i & 3;
    const int k   = kb4 * 4 + kk;
    const int j   = (c >> 4) * 256 + uc * 16 + (c & 15);
    wsf[PWHH0_F + i] = Whh0[j * 256 + k];
    wsf[PWIH1_F + i] = Wih1[j * 256 + k];
    wsf[PWHH1_F + i] = Whh1[j * 256 + k];
    if (k < 16) wsf[PWIH0_F + uc * 1024 + k * 64 + c] = Wih0[j * 16 + k];
  }
}

__global__ __launch_bounds__(TPB) void lstm_main(
    const float* __restrict__ traj,
    const float* __restrict__ bih0, const float* __restrict__ bhh0,
    const float* __restrict__ bih1, const float* __restrict__ bhh1,
    const float* __restrict__ Wlin, const float* __restrict__ blin,
    float* __restrict__ out, float* __restrict__ wsf) {
  // sh_a[16][256] | sh_bp[8][16][64] (B-tile first 4096 / partials) |
  // sh_x[16][16] | sh_g[16][64] | sh_hn[16][16]  => 13824 floats = 55.3 KB
  __shared__ float smem[13824];
  float* sh_a  = smem;
  float* sh_bp = smem + 4096;
  float* sh_x  = smem + 12288;
  float* sh_g  = smem + 12544;
  float* sh_hn = smem + 13568;

  const int tid = threadIdx.x;
  const int wg  = blockIdx.x;
  const int rt  = wg >> 4;        // row tile (16 rows), 0..15 == group id
  const int uc  = wg & 15;        // unit chunk (16 hidden units)
  const int slotId  = rt >> 1;    // pipeline slot 0..7
  const int rowBase = rt << 4;

  const int ks = tid >> 6;        // K-split 0..7 (== wave id: uniform/wave)
  const int c  = tid & 63;        // packed col 0..63 (gate*16+unit)

  unsigned* ctrl = (unsigned*)wsf;
  unsigned* gcnt = &ctrl[GRP_U(rt)];

  const float4* PW_hh0 = (const float4*)(wsf + PWHH0_F + uc * 16384);
  const float4* PW_ih1 = (const float4*)(wsf + PWIH1_F + uc * 16384);
  const float4* PW_hh1 = (const float4*)(wsf + PWHH1_F + uc * 16384);
  const float*  PW_ih0 = wsf + PWIH0_F + uc * 1024;

  unsigned bar = 0;
  float acc[16];

  for (int g = 0; g < 127; ++g) {
    const int s = (g - slotId) & 7;
    const int t = g - s;
    const bool valid = (t >= 0) && (t <= 119);
    const bool fresh = (s == 0) || (!valid);
    const int p = g & 1;

    // ================= PHASE A : layer 0 =================
    if (g >= 8) {  // need out[:, g-8] finalized
      if (tid == 0) {
        const unsigned need = (unsigned)(g - 7);
        while (aload(&ctrl[RDY_U(rt)]) < need) __builtin_amdgcn_s_sleep(2);
      }
      __syncthreads();
    }
    if (tid < 256) {  // stage x[16 rows][16]
      const int r = tid >> 4, d = tid & 15;
      const int b = (rowBase + r) & 31;
      float xv = 0.0f;
      if (valid) {
        if (t <= 7 && s < 8 - t) {
          xv = traj[b * 2048 + (t + s) * 16 + d];
        } else if (d < 8) {
          const int ti = (t <= 7) ? (2 * t + s - 1) : (t + s);
          xv = traj[b * 2048 + ti * 16 + d];
        } else {
          xv = out[b * 960 + (t + s - 8) * 8 + (d - 8)];
        }
      }
      sh_x[tid] = xv;
    }
    {  // stage h0prev (2 float4 per thread)
      const float* h0r = wsf + (p ? H0B_F : H0A_F) + rowBase * 256;
      float4* A4 = (float4*)sh_a;
#pragma unroll
      for (int i = 0; i < 2; ++i) {
        const int idx = tid + i * 512;
        float4 v = make_float4(0.f, 0.f, 0.f, 0.f);
        if (!fresh) v = ((const float4*)h0r)[idx];
        A4[idx] = v;
      }
    }
    __syncthreads();

#pragma unroll
    for (int r = 0; r < 16; ++r) acc[r] = 0.f;
    {  // x part, K=16 (2 k's per ks)
#pragma unroll
      for (int kk = 0; kk < 2; ++kk) {
        const int k = ks * 2 + kk;
        const float w = PW_ih0[k * 64 + c];
#pragma unroll
        for (int r = 0; r < 16; ++r)
          acc[r] = fmaf(sh_x[r * 16 + k], w, acc[r]);
      }
    }
    {  // h part, K=256: 8 float4 weight loads, broadcast LDS h-reads
      const float4* A4 = (const float4*)sh_a;
#pragma unroll
      for (int kc = 0; kc < 8; ++kc) {
        const int kb4 = ks * 8 + kc;
        const float4 w4 = PW_hh0[kb4 * 64 + c];
#pragma unroll
        for (int r = 0; r < 16; ++r) {
          const float4 h4 = A4[r * 64 + kb4];
          acc[r] = fmaf(h4.x, w4.x, acc[r]);
          acc[r] = fmaf(h4.y, w4.y, acc[r]);
          acc[r] = fmaf(h4.z, w4.z, acc[r]);
          acc[r] = fmaf(h4.w, w4.w, acc[r]);
        }
      }
    }
    {  // partials -> LDS [ks][16][64] (lanes consecutive: conflict-free)
#pragma unroll
      for (int r = 0; r < 16; ++r)
        sh_bp[ks * 1024 + r * 64 + c] = acc[r];
    }
    __syncthreads();
    {  // reduce K-splits + bias -> sh_g[16][64] (2 outputs/thread)
#pragma unroll
      for (int e = 0; e < 2; ++e) {
        const int oi = tid + e * 512;
        const int lc = oi & 63;
        const int j = (lc >> 4) * 256 + uc * 16 + (lc & 15);
        float sum = bih0[j] + bhh0[j];
#pragma unroll
        for (int kq = 0; kq < 8; ++kq) sum += sh_bp[kq * 1024 + oi];
        sh_g[oi] = sum;
      }
    }
    __syncthreads();
    if (tid < 256) {  // LSTM update, layer 0
      const int r = tid >> 4, u = tid & 15;
      const int grow = rowBase + r;
      const int gu = uc * 16 + u;
      const float iv = sh_g[r * 64 + u];
      const float fv = sh_g[r * 64 + 16 + u];
      const float gv = sh_g[r * 64 + 32 + u];
      const float ov = sh_g[r * 64 + 48 + u];
      const float cold = fresh ? 0.f : wsf[C0_F + grow * 256 + gu];
      const float cn = sigf(fv) * cold + sigf(iv) * tanhfast(gv);
      const float hn = sigf(ov) * tanhfast(cn);
      wsf[C0_F + grow * 256 + gu] = cn;
      wsf[(p ? H0A_F : H0B_F) + grow * 256 + gu] = hn;
    }
    bar += 16;
    groupbar(gcnt, bar);

    // ================= PHASE B : layer 1 =================
    {  // stage h0' -> sh_a ; h1prev -> sh_bp
      const float* h0w = wsf + (p ? H0A_F : H0B_F) + rowBase * 256;
      const float* h1r = wsf + (p ? H1B_F : H1A_F) + rowBase * 256;
      float4* A4 = (float4*)sh_a;
      float4* B4 = (float4*)sh_bp;
#pragma unroll
      for (int i = 0; i < 2; ++i) {
        const int idx = tid + i * 512;
        A4[idx] = ((const float4*)h0w)[idx];
        float4 v = make_float4(0.f, 0.f, 0.f, 0.f);
        if (!fresh) v = ((const float4*)h1r)[idx];
        B4[idx] = v;
      }
    }
    __syncthreads();

#pragma unroll
    for (int r = 0; r < 16; ++r) acc[r] = 0.f;
    {  // fused (h0' @ Wih1^T) + (h1 @ Whh1^T)
      const float4* A4 = (const float4*)sh_a;
      const float4* B4 = (const float4*)sh_bp;
#pragma unroll
      for (int kc = 0; kc < 8; ++kc) {
        const int kb4 = ks * 8 + kc;
        const float4 wa = PW_ih1[kb4 * 64 + c];
        const float4 wb = PW_hh1[kb4 * 64 + c];
#pragma unroll
        for (int r = 0; r < 16; ++r) {
          const float4 a4 = A4[r * 64 + kb4];
          const float4 b4 = B4[r * 64 + kb4];
          acc[r] = fmaf(a4.x, wa.x, acc[r]);
          acc[r] = fmaf(a4.y, wa.y, acc[r]);
          acc[r] = fmaf(a4.z, wa.z, acc[r]);
          acc[r] = fmaf(a4.w, wa.w, acc[r]);
          acc[r] = fmaf(b4.x, wb.x, acc[r]);
          acc[r] = fmaf(b4.y, wb.y, acc[r]);
          acc[r] = fmaf(b4.z, wb.z, acc[r]);
          acc[r] = fmaf(b4.w, wb.w, acc[r]);
        }
      }
    }
    __syncthreads();  // sh_bp B-tile dead; reuse as partials
    {
#pragma unroll
      for (int r = 0; r < 16; ++r)
        sh_bp[ks * 1024 + r * 64 + c] = acc[r];
    }
    __syncthreads();
    {
#pragma unroll
      for (int e = 0; e < 2; ++e) {
        const int oi = tid + e * 512;
        const int lc = oi & 63;
        const int j = (lc >> 4) * 256 + uc * 16 + (lc & 15);
        float sum = bih1[j] + bhh1[j];
#pragma unroll
        for (int kq = 0; kq < 8; ++kq) sum += sh_bp[kq * 1024 + oi];
        sh_g[oi] = sum;
      }
    }
    __syncthreads();
    if (tid < 256) {  // LSTM update, layer 1
      const int r = tid >> 4, u = tid & 15;
      const int grow = rowBase + r;
      const int gu = uc * 16 + u;
      const float iv = sh_g[r * 64 + u];
      const float fv = sh_g[r * 64 + 16 + u];
      const float gv = sh_g[r * 64 + 32 + u];
      const float ov = sh_g[r * 64 + 48 + u];
      const float cold = fresh ? 0.f : wsf[C1_F + grow * 256 + gu];
      const float cn = sigf(fv) * cold + sigf(iv) * tanhfast(gv);
      const float hn = sigf(ov) * tanhfast(cn);
      wsf[C1_F + grow * 256 + gu] = cn;
      wsf[(p ? H1A_F : H1B_F) + grow * 256 + gu] = hn;
      sh_hn[r * 16 + u] = hn;
    }
    __syncthreads();
    {  // head + column finalize handshake
      const int tf = g - 7;
      const bool isHead = (tf >= 0) && (slotId == (tf & 7));
      if (isHead) {
        if (tid < 128) {
          const int rl = tid >> 3, o = tid & 7;
          float sum = 0.f;
#pragma unroll
          for (int u = 0; u < 16; ++u)
            sum += sh_hn[rl * 16 + u] * Wlin[o * 256 + uc * 16 + u];
          const int b = ((rt & 1) << 4) + rl;
          atomicAdd(&wsf[PSUM_F + tf * 256 + b * 8 + o], sum);
        }
        __syncthreads();
        if (tid == 0) {
          __threadfence();
          atomicAdd(&ctrl[PCNT_U(tf)], 1u);
        }
        if (((rt & 1) == 1) && (uc == 15)) {  // finisher wg
          if (tid == 0)
            while (aload(&ctrl[PCNT_U(tf)]) < 32u) __builtin_amdgcn_s_sleep(1);
          __syncthreads();
          if (tid < 256) {
            const int b = tid >> 3, o = tid & 7;
            const float base = (tf == 0) ? traj[b * 2048 + 7 * 16 + 8 + o]
                                         : out[b * 960 + (tf - 1) * 8 + o];
            out[b * 960 + tf * 8 + o] =
                base + blin[o] + wsf[PSUM_F + tf * 256 + tid];
          }
          __syncthreads();
          if (tid < 16) {
            __threadfence();
            __hip_atomic_store(&ctrl[RDY_U(tid)], (unsigned)(tf + 1),
                               __ATOMIC_RELEASE, __HIP_MEMORY_SCOPE_AGENT);
          }
        }
      }
    }
    bar += 16;
    groupbar(gcnt, bar);
  }

  // ---- epilogue: h_n/c_n for window 119 (rows 224..255, buffers B).
  if (rt >= 14) {
    if (tid == 0) {
      __threadfence();
      atomicAdd(&ctrl[END_U], 1u);
      while (aload(&ctrl[END_U]) < 32u) __builtin_amdgcn_s_sleep(2);
    }
    __syncthreads();
    const int idx = (rt - 14) * 16 + uc;   // 0..31
    const int i = idx * 1024 + tid * 2;    // 0..32767, step 2
    const int part = i >> 14;
    const int l = (i >> 13) & 1;
    const int b = (i >> 8) & 31;
    const int u = i & 255;
    const float* src =
        (part == 0) ? (l == 0 ? wsf + H0B_F : wsf + H1B_F)
                    : (l == 0 ? wsf + C0_F  : wsf + C1_F);
    const float2 v = *(const float2*)(src + (224 + b) * 256 + u);
    *(float2*)(out + 30720 + i) = v;
  }
}

extern "C" void kernel_launch(void* const* d_in, const int* in_sizes, int n_in,
                              void* d_out, int out_size, void* d_ws, size_t ws_size,
                              hipStream_t stream) {
  (void)in_sizes; (void)n_in; (void)out_size; (void)ws_size;
  const float* traj = (const float*)d_in[0];
  const float* Wih0 = (const float*)d_in[1];
  const float* Whh0 = (const float*)d_in[2];
  const float* bih0 = (const float*)d_in[3];
  const float* bhh0 = (const float*)d_in[4];
  const float* Wih1 = (const float*)d_in[5];
  const float* Whh1 = (const float*)d_in[6];
  const float* bih1 = (const float*)d_in[7];
  const float* bhh1 = (const float*)d_in[8];
  const float* Wlin = (const float*)d_in[9];
  const float* blin = (const float*)d_in[10];
  float* out = (float*)d_out;
  float* wsf = (float*)d_ws;

  hipMemsetAsync(d_ws, 0, CTRL_BYTES, stream);
  lstm_prep<<<1024, 256, 0, stream>>>(Wih0, Whh0, Wih1, Whh1, wsf);

  void* args[] = {(void*)&traj, (void*)&bih0, (void*)&bhh0, (void*)&bih1,
                  (void*)&bhh1, (void*)&Wlin, (void*)&blin, (void*)&out,
                  (void*)&wsf};
  hipLaunchCooperativeKernel((void*)lstm_main, dim3(NWG), dim3(TPB), args, 0,
                             stream);
}